// Round 2
// baseline (793.921 us; speedup 1.0000x reference)
//
#include <hip/hip_runtime.h>

#define NCLS   4096
#define BATCHN 65536
#define TOPK   4096
#define ALPHA  2.0f
#define GRID_RL 2048

// ---------------------------------------------------------------------------
// Kernel 0: detect whether link_table arrived as int32 (words all 0/1) or as
// 1-byte bool (packed bytes -> many words > 1). Deterministic for the dataset.
// ---------------------------------------------------------------------------
__global__ void detect_int32_kernel(const unsigned int* __restrict__ lt,
                                    int* __restrict__ flag) {
    int tid = threadIdx.x;  // 64 threads
    unsigned int bad = 0;
    for (int i = tid; i < 1024; i += 64) bad |= (lt[i] > 1u) ? 1u : 0u;
    unsigned long long mask = __ballot(bad != 0);
    if (tid == 0) flag[0] = (mask == 0ULL) ? 1 : 0;  // 1 => int32 storage
}

// ---------------------------------------------------------------------------
// Kernel 1: persistent blocks, 32 rows each, register double-buffer so next
// row's 16 global loads are in flight across this row's barriers/reductions.
// Also builds the level-1 (bits 31:20) radix histogram for the top-k kernel.
// ---------------------------------------------------------------------------
__global__ __launch_bounds__(256) void row_loss_kernel(
    const float* __restrict__ yp, const int* __restrict__ yt,
    const unsigned char* __restrict__ lt, const int* __restrict__ flag,
    float* __restrict__ losses, unsigned int* __restrict__ hist) {
    const int tid  = threadIdx.x;
    const int wid  = tid >> 6, lane = tid & 63;

    __shared__ float wmax[4];
    __shared__ float wsum[4];
    __shared__ int   widx[4];
    __shared__ float s_true;

    int b = blockIdx.x;
    {
        const float4* rp = reinterpret_cast<const float4*>(yp + (size_t)b * NCLS);
        // fallthrough into loop with cur loaded
        float4 c0 = rp[tid], c1 = rp[256 + tid], c2 = rp[512 + tid], c3 = rp[768 + tid];

        while (b < BATCHN) {
            const int nb = b + GRID_RL;
            float4 n0, n1, n2, n3;
            if (nb < BATCHN) {   // uniform branch; loads issued before the barriers below
                const float4* np_ = reinterpret_cast<const float4*>(yp + (size_t)nb * NCLS);
                n0 = np_[tid]; n1 = np_[256 + tid]; n2 = np_[512 + tid]; n3 = np_[768 + tid];
            }

            // ---- local max (value only: 1 op/elem)
            float m = fmaxf(fmaxf(fmaxf(c0.x, c0.y), fmaxf(c0.z, c0.w)),
                            fmaxf(fmaxf(c1.x, c1.y), fmaxf(c1.z, c1.w)));
            m = fmaxf(m, fmaxf(fmaxf(fmaxf(c2.x, c2.y), fmaxf(c2.z, c2.w)),
                               fmaxf(fmaxf(c3.x, c3.y), fmaxf(c3.z, c3.w))));
            #pragma unroll
            for (int off = 32; off > 0; off >>= 1)
                m = fmaxf(m, __shfl_xor(m, off, 64));
            if (lane == 0) wmax[wid] = m;

            const int gt = yt[b];  // uniform -> scalar load
            if (tid == ((gt >> 2) & 255)) {
                const int j = gt >> 10, k = gt & 3;
                float4 vv = (j == 0) ? c0 : (j == 1) ? c1 : (j == 2) ? c2 : c3;
                s_true = (k == 0) ? vv.x : (k == 1) ? vv.y : (k == 2) ? vv.z : vv.w;
            }
            __syncthreads();
            const float M = fmaxf(fmaxf(wmax[0], wmax[1]), fmaxf(wmax[2], wmax[3]));

            // ---- first index equal to M (descending chain => smallest wins)
            const int base = tid * 4;
            int idx = 0x7fffffff;
            if (c3.w == M) idx = 3072 + base + 3;
            if (c3.z == M) idx = 3072 + base + 2;
            if (c3.y == M) idx = 3072 + base + 1;
            if (c3.x == M) idx = 3072 + base + 0;
            if (c2.w == M) idx = 2048 + base + 3;
            if (c2.z == M) idx = 2048 + base + 2;
            if (c2.y == M) idx = 2048 + base + 1;
            if (c2.x == M) idx = 2048 + base + 0;
            if (c1.w == M) idx = 1024 + base + 3;
            if (c1.z == M) idx = 1024 + base + 2;
            if (c1.y == M) idx = 1024 + base + 1;
            if (c1.x == M) idx = 1024 + base + 0;
            if (c0.w == M) idx = base + 3;
            if (c0.z == M) idx = base + 2;
            if (c0.y == M) idx = base + 1;
            if (c0.x == M) idx = base + 0;

            // ---- exp sum
            float sum = 0.f;
            sum += __expf(c0.x - M); sum += __expf(c0.y - M);
            sum += __expf(c0.z - M); sum += __expf(c0.w - M);
            sum += __expf(c1.x - M); sum += __expf(c1.y - M);
            sum += __expf(c1.z - M); sum += __expf(c1.w - M);
            sum += __expf(c2.x - M); sum += __expf(c2.y - M);
            sum += __expf(c2.z - M); sum += __expf(c2.w - M);
            sum += __expf(c3.x - M); sum += __expf(c3.y - M);
            sum += __expf(c3.z - M); sum += __expf(c3.w - M);

            #pragma unroll
            for (int off = 32; off > 0; off >>= 1) {
                sum += __shfl_xor(sum, off, 64);
                idx  = min(idx, __shfl_xor(idx, off, 64));
            }
            if (lane == 0) { wsum[wid] = sum; widx[wid] = idx; }
            __syncthreads();

            if (tid == 0) {
                const float tot = wsum[0] + wsum[1] + wsum[2] + wsum[3];
                const int pred  = min(min(widx[0], widx[1]), min(widx[2], widx[3]));
                const float ce  = logf(tot) + M - s_true;
                float factor = 1.0f;
                if (pred != gt) {
                    const size_t li = (size_t)gt * NCLS + (size_t)pred;
                    const int linked = flag[0] ? ((const int*)lt)[li] : (int)lt[li];
                    if (linked) factor = ALPHA;
                }
                const float lv = factor * ce;
                losses[b] = lv;
                atomicAdd(&hist[__float_as_uint(lv) >> 20], 1u);
            }
            __syncthreads();  // protect s_true/wmax from next iteration's writes

            b = nb;
            c0 = n0; c1 = n1; c2 = n2; c3 = n3;
        }
    }
}

// ---------------------------------------------------------------------------
// Kernel 2: exact mean of top-K. Level-1 hist comes precomputed; threshold
// scans are single-wave suffix-scan + ballot (no serial thread-0 loops).
// ---------------------------------------------------------------------------
__device__ inline void scan4096(const unsigned int* hist, unsigned int kneed,
                                int* s_bin, unsigned int* s_kneed, int tid) {
    if (tid < 64) {
        // stage 1: super-bins of 64
        unsigned int sb = 0;
        #pragma unroll 8
        for (int i = 0; i < 64; ++i) sb += hist[tid * 64 + i];
        unsigned int GS = sb;  // suffix sum over super-bins
        #pragma unroll
        for (int off = 1; off < 64; off <<= 1) {
            unsigned int o = __shfl_down(GS, off, 64);
            GS += (tid + off < 64) ? o : 0u;
        }
        unsigned long long b1 = __ballot(GS >= kneed);
        const int sstar = 63 - __clzll(b1);
        const unsigned int A1 = (sstar < 63) ? __shfl(GS, sstar + 1, 64) : 0u;

        // stage 2: within super-bin sstar
        unsigned int W = hist[sstar * 64 + tid];
        #pragma unroll
        for (int off = 1; off < 64; off <<= 1) {
            unsigned int o = __shfl_down(W, off, 64);
            W += (tid + off < 64) ? o : 0u;
        }
        unsigned long long b2 = __ballot(A1 + W >= kneed);
        const int tstar = 63 - __clzll(b2);
        const unsigned int above = A1 + ((tstar < 63) ? __shfl(W, tstar + 1, 64) : 0u);
        if (tid == 0) { *s_bin = sstar * 64 + tstar; *s_kneed = kneed - above; }
    }
}

__global__ __launch_bounds__(1024) void topk_mean_kernel(
    const float* __restrict__ losses, const unsigned int* __restrict__ ghist,
    float* __restrict__ out) {
    __shared__ unsigned int hist[4096];
    __shared__ int          s_bin;
    __shared__ unsigned int s_kneed;
    __shared__ double       dsum[16];
    __shared__ unsigned int dcnt[16];

    const int tid = threadIdx.x;
    const int N = BATCHN, K = TOPK;

    // ---- level 1: bits [31:20] (hist precomputed by row_loss)
    for (int i = tid; i < 4096; i += 1024) hist[i] = ghist[i];
    __syncthreads();
    scan4096(hist, (unsigned int)K, &s_bin, &s_kneed, tid);
    __syncthreads();
    const unsigned int t1 = (unsigned int)s_bin;
    const unsigned int k1 = s_kneed;
    __syncthreads();

    // ---- level 2: bits [19:8] among keys with key>>20 == t1
    for (int i = tid; i < 4096; i += 1024) hist[i] = 0;
    __syncthreads();
    for (int i = tid; i < N; i += 1024) {
        const unsigned int key = __float_as_uint(losses[i]);
        if ((key >> 20) == t1) atomicAdd(&hist[(key >> 8) & 0xFFFu], 1u);
    }
    __syncthreads();
    scan4096(hist, k1, &s_bin, &s_kneed, tid);
    __syncthreads();
    const unsigned int t2 = (unsigned int)s_bin;
    const unsigned int k2 = s_kneed;
    const unsigned int pref = (t1 << 12) | t2;  // 24-bit prefix
    __syncthreads();

    // ---- level 3: bits [7:0] among keys with key>>8 == pref
    for (int i = tid; i < 256; i += 1024) hist[i] = 0;
    __syncthreads();
    for (int i = tid; i < N; i += 1024) {
        const unsigned int key = __float_as_uint(losses[i]);
        if ((key >> 8) == pref) atomicAdd(&hist[key & 0xFFu], 1u);
    }
    __syncthreads();
    if (tid < 64) {
        // super-bins of 4
        unsigned int sb = hist[tid * 4] + hist[tid * 4 + 1] +
                          hist[tid * 4 + 2] + hist[tid * 4 + 3];
        unsigned int GS = sb;
        #pragma unroll
        for (int off = 1; off < 64; off <<= 1) {
            unsigned int o = __shfl_down(GS, off, 64);
            GS += (tid + off < 64) ? o : 0u;
        }
        unsigned long long b1 = __ballot(GS >= k2);
        const int sstar = 63 - __clzll(b1);
        const unsigned int A1 = (sstar < 63) ? __shfl(GS, sstar + 1, 64) : 0u;
        if (tid == 0) {
            unsigned int G = A1; int tstar = sstar * 4; unsigned int above = A1;
            for (int j = 3; j >= 0; --j) {
                const int bin = sstar * 4 + j;
                if (G + hist[bin] >= k2) { tstar = bin; above = G; break; }
                G += hist[bin];
            }
            s_bin = tstar; s_kneed = k2 - above; (void)s_kneed;
        }
    }
    __syncthreads();
    const unsigned int T = (pref << 8) | (unsigned int)s_bin;  // threshold bits

    // ---- final: sum strictly-greater, fill remainder with T (ties)
    double local = 0.0; unsigned int cgt = 0;
    for (int i = tid; i < N; i += 1024) {
        const unsigned int key = __float_as_uint(losses[i]);
        if (key > T) { local += (double)__uint_as_float(key); cgt++; }
    }
    const int wid = tid >> 6, lane = tid & 63;
    #pragma unroll
    for (int off = 32; off > 0; off >>= 1) {
        local += __shfl_down(local, off, 64);
        cgt   += __shfl_down(cgt, off, 64);
    }
    if (lane == 0) { dsum[wid] = local; dcnt[wid] = cgt; }
    __syncthreads();
    if (tid == 0) {
        double tot = 0.0; unsigned int ngt = 0;
        for (int w = 0; w < 16; ++w) { tot += dsum[w]; ngt += dcnt[w]; }
        tot += (double)(K - ngt) * (double)__uint_as_float(T);
        out[0] = (float)(tot / (double)K);
    }
}

// ---------------------------------------------------------------------------
extern "C" void kernel_launch(void* const* d_in, const int* in_sizes, int n_in,
                              void* d_out, int out_size, void* d_ws, size_t ws_size,
                              hipStream_t stream) {
    const float* y_pred     = (const float*)d_in[0];
    const int* y_true       = (const int*)d_in[1];
    const unsigned char* lt = (const unsigned char*)d_in[2];
    float* out              = (float*)d_out;

    int*          flag   = (int*)d_ws;
    unsigned int* hist   = (unsigned int*)((char*)d_ws + 1024);          // 16 KB
    float*        losses = (float*)((char*)d_ws + 32768);                // 256 KB

    detect_int32_kernel<<<1, 64, 0, stream>>>((const unsigned int*)lt, flag);
    hipMemsetAsync(hist, 0, 4096 * sizeof(unsigned int), stream);
    row_loss_kernel<<<GRID_RL, 256, 0, stream>>>(y_pred, y_true, lt, flag, losses, hist);
    topk_mean_kernel<<<1, 1024, 0, stream>>>(losses, hist, out);
}

// Round 3
// 758.372 us; speedup vs baseline: 1.0469x; 1.0469x over previous
//
#include <hip/hip_runtime.h>

#define NCLS   4096
#define BATCHN 65536
#define TOPK   4096
#define ALPHA  2.0f

// ---------------------------------------------------------------------------
// Kernel 0: detect whether link_table arrived as int32 (words all 0/1) or as
// 1-byte bool (packed bytes -> many words > 1). Deterministic for the dataset.
// ---------------------------------------------------------------------------
__global__ void detect_int32_kernel(const unsigned int* __restrict__ lt,
                                    int* __restrict__ flag) {
    int tid = threadIdx.x;  // 64 threads
    unsigned int bad = 0;
    for (int i = tid; i < 1024; i += 64) bad |= (lt[i] > 1u) ? 1u : 0u;
    unsigned long long mask = __ballot(bad != 0);
    if (tid == 0) flag[0] = (mask == 0ULL) ? 1 : 0;  // 1 => int32 storage
}

// ---------------------------------------------------------------------------
// Kernel 1: ONE WAVE PER ROW. No barriers, no LDS, row held in registers
// (statically-indexed v[16] -> stays in VGPRs). All reductions via shuffles.
// Also builds the level-1 (bits 31:20) radix histogram for the top-k kernel.
// ---------------------------------------------------------------------------
__global__ __launch_bounds__(256) void row_loss_kernel(
    const float* __restrict__ yp, const int* __restrict__ yt,
    const unsigned char* __restrict__ lt, const int* __restrict__ flag,
    float* __restrict__ losses, unsigned int* __restrict__ hist) {
    const int lane = threadIdx.x & 63;
    const int wv   = threadIdx.x >> 6;
    const int b    = blockIdx.x * 4 + wv;          // grid = BATCHN/4 exactly

    const float4* rp = reinterpret_cast<const float4*>(yp + (size_t)b * NCLS);
    float4 v[16];
    #pragma unroll
    for (int j = 0; j < 16; ++j) v[j] = rp[j * 64 + lane];

    // ---- row max (value only)
    float m = -3.4e38f;
    #pragma unroll
    for (int j = 0; j < 16; ++j)
        m = fmaxf(m, fmaxf(fmaxf(v[j].x, v[j].y), fmaxf(v[j].z, v[j].w)));
    #pragma unroll
    for (int off = 32; off > 0; off >>= 1)
        m = fmaxf(m, __shfl_xor(m, off, 64));
    // m == row max M on every lane now

    // ---- first index equal to M (descending chain => smallest wins per lane)
    int idx = 0x7fffffff;
    #pragma unroll
    for (int j = 15; j >= 0; --j) {
        const int c = j * 256 + lane * 4;          // col of v[j].x for this lane
        if (v[j].w == m) idx = c + 3;
        if (v[j].z == m) idx = c + 2;
        if (v[j].y == m) idx = c + 1;
        if (v[j].x == m) idx = c + 0;
    }

    // ---- exp sum (4 independent accumulators to break the add chain)
    float sx = 0.f, sy = 0.f, sz = 0.f, sw = 0.f;
    #pragma unroll
    for (int j = 0; j < 16; ++j) {
        sx += __expf(v[j].x - m);
        sy += __expf(v[j].y - m);
        sz += __expf(v[j].z - m);
        sw += __expf(v[j].w - m);
    }
    float sum = (sx + sy) + (sz + sw);

    #pragma unroll
    for (int off = 32; off > 0; off >>= 1) {
        sum += __shfl_xor(sum, off, 64);
        idx  = min(idx, __shfl_xor(idx, off, 64));
    }

    // ---- true-class logit: owner lane -> broadcast
    const int gt = yt[b];                           // wave-uniform scalar load
    const int jg = gt >> 8, lg = (gt >> 2) & 63, kg = gt & 3;
    float4 tv = v[0];
    #pragma unroll
    for (int j = 1; j < 16; ++j) if (jg == j) tv = v[j];   // static indices
    float tval = (kg == 0) ? tv.x : (kg == 1) ? tv.y : (kg == 2) ? tv.z : tv.w;
    tval = __shfl(tval, lg, 64);

    if (lane == 0) {
        const float ce = logf(sum) + m - tval;
        const int pred = idx;
        float factor = 1.0f;
        if (pred != gt) {
            const size_t li = (size_t)gt * NCLS + (size_t)pred;
            const int linked = flag[0] ? ((const int*)lt)[li] : (int)lt[li];
            if (linked) factor = ALPHA;
        }
        const float lv = factor * ce;
        losses[b] = lv;
        atomicAdd(&hist[__float_as_uint(lv) >> 20], 1u);
    }
}

// ---------------------------------------------------------------------------
// Kernel 2: exact mean of top-K. Level-1 hist comes precomputed; threshold
// scans are single-wave suffix-scan + ballot (no serial thread-0 loops).
// ---------------------------------------------------------------------------
__device__ inline void scan4096(const unsigned int* hist, unsigned int kneed,
                                int* s_bin, unsigned int* s_kneed, int tid) {
    if (tid < 64) {
        // stage 1: super-bins of 64
        unsigned int sb = 0;
        #pragma unroll 8
        for (int i = 0; i < 64; ++i) sb += hist[tid * 64 + i];
        unsigned int GS = sb;  // suffix sum over super-bins
        #pragma unroll
        for (int off = 1; off < 64; off <<= 1) {
            unsigned int o = __shfl_down(GS, off, 64);
            GS += (tid + off < 64) ? o : 0u;
        }
        unsigned long long b1 = __ballot(GS >= kneed);
        const int sstar = 63 - __clzll(b1);
        const unsigned int A1 = (sstar < 63) ? __shfl(GS, sstar + 1, 64) : 0u;

        // stage 2: within super-bin sstar
        unsigned int W = hist[sstar * 64 + tid];
        #pragma unroll
        for (int off = 1; off < 64; off <<= 1) {
            unsigned int o = __shfl_down(W, off, 64);
            W += (tid + off < 64) ? o : 0u;
        }
        unsigned long long b2 = __ballot(A1 + W >= kneed);
        const int tstar = 63 - __clzll(b2);
        const unsigned int above = A1 + ((tstar < 63) ? __shfl(W, tstar + 1, 64) : 0u);
        if (tid == 0) { *s_bin = sstar * 64 + tstar; *s_kneed = kneed - above; }
    }
}

__global__ __launch_bounds__(1024) void topk_mean_kernel(
    const float* __restrict__ losses, const unsigned int* __restrict__ ghist,
    float* __restrict__ out) {
    __shared__ unsigned int hist[4096];
    __shared__ int          s_bin;
    __shared__ unsigned int s_kneed;
    __shared__ double       dsum[16];
    __shared__ unsigned int dcnt[16];

    const int tid = threadIdx.x;
    const int N = BATCHN, K = TOPK;

    // ---- level 1: bits [31:20] (hist precomputed by row_loss)
    for (int i = tid; i < 4096; i += 1024) hist[i] = ghist[i];
    __syncthreads();
    scan4096(hist, (unsigned int)K, &s_bin, &s_kneed, tid);
    __syncthreads();
    const unsigned int t1 = (unsigned int)s_bin;
    const unsigned int k1 = s_kneed;
    __syncthreads();

    // ---- level 2: bits [19:8] among keys with key>>20 == t1
    for (int i = tid; i < 4096; i += 1024) hist[i] = 0;
    __syncthreads();
    for (int i = tid; i < N; i += 1024) {
        const unsigned int key = __float_as_uint(losses[i]);
        if ((key >> 20) == t1) atomicAdd(&hist[(key >> 8) & 0xFFFu], 1u);
    }
    __syncthreads();
    scan4096(hist, k1, &s_bin, &s_kneed, tid);
    __syncthreads();
    const unsigned int t2 = (unsigned int)s_bin;
    const unsigned int k2 = s_kneed;
    const unsigned int pref = (t1 << 12) | t2;  // 24-bit prefix
    __syncthreads();

    // ---- level 3: bits [7:0] among keys with key>>8 == pref
    for (int i = tid; i < 256; i += 1024) hist[i] = 0;
    __syncthreads();
    for (int i = tid; i < N; i += 1024) {
        const unsigned int key = __float_as_uint(losses[i]);
        if ((key >> 8) == pref) atomicAdd(&hist[key & 0xFFu], 1u);
    }
    __syncthreads();
    if (tid < 64) {
        // super-bins of 4
        unsigned int sb = hist[tid * 4] + hist[tid * 4 + 1] +
                          hist[tid * 4 + 2] + hist[tid * 4 + 3];
        unsigned int GS = sb;
        #pragma unroll
        for (int off = 1; off < 64; off <<= 1) {
            unsigned int o = __shfl_down(GS, off, 64);
            GS += (tid + off < 64) ? o : 0u;
        }
        unsigned long long b1 = __ballot(GS >= k2);
        const int sstar = 63 - __clzll(b1);
        const unsigned int A1 = (sstar < 63) ? __shfl(GS, sstar + 1, 64) : 0u;
        if (tid == 0) {
            unsigned int G = A1; int tstar = sstar * 4;
            for (int j = 3; j >= 0; --j) {
                const int bin = sstar * 4 + j;
                if (G + hist[bin] >= k2) { tstar = bin; break; }
                G += hist[bin];
            }
            s_bin = tstar;
        }
    }
    __syncthreads();
    const unsigned int T = (pref << 8) | (unsigned int)s_bin;  // threshold bits

    // ---- final: sum strictly-greater, fill remainder with T (ties)
    double local = 0.0; unsigned int cgt = 0;
    for (int i = tid; i < N; i += 1024) {
        const unsigned int key = __float_as_uint(losses[i]);
        if (key > T) { local += (double)__uint_as_float(key); cgt++; }
    }
    const int wid = tid >> 6, lane = tid & 63;
    #pragma unroll
    for (int off = 32; off > 0; off >>= 1) {
        local += __shfl_down(local, off, 64);
        cgt   += __shfl_down(cgt, off, 64);
    }
    if (lane == 0) { dsum[wid] = local; dcnt[wid] = cgt; }
    __syncthreads();
    if (tid == 0) {
        double tot = 0.0; unsigned int ngt = 0;
        for (int w = 0; w < 16; ++w) { tot += dsum[w]; ngt += dcnt[w]; }
        tot += (double)(K - ngt) * (double)__uint_as_float(T);
        out[0] = (float)(tot / (double)K);
    }
}

// ---------------------------------------------------------------------------
extern "C" void kernel_launch(void* const* d_in, const int* in_sizes, int n_in,
                              void* d_out, int out_size, void* d_ws, size_t ws_size,
                              hipStream_t stream) {
    const float* y_pred     = (const float*)d_in[0];
    const int* y_true       = (const int*)d_in[1];
    const unsigned char* lt = (const unsigned char*)d_in[2];
    float* out              = (float*)d_out;

    int*          flag   = (int*)d_ws;
    unsigned int* hist   = (unsigned int*)((char*)d_ws + 1024);          // 16 KB
    float*        losses = (float*)((char*)d_ws + 32768);                // 256 KB

    detect_int32_kernel<<<1, 64, 0, stream>>>((const unsigned int*)lt, flag);
    hipMemsetAsync(hist, 0, 4096 * sizeof(unsigned int), stream);
    row_loss_kernel<<<BATCHN / 4, 256, 0, stream>>>(y_pred, y_true, lt, flag, losses, hist);
    topk_mean_kernel<<<1, 1024, 0, stream>>>(losses, hist, out);
}

// Round 4
// 755.882 us; speedup vs baseline: 1.0503x; 1.0033x over previous
//
#include <hip/hip_runtime.h>

#define NCLS   4096
#define BATCHN 65536
#define TOPK   4096
#define ALPHA  2.0f

// ---------------------------------------------------------------------------
// Kernel 0: detect whether link_table arrived as int32 (words all 0/1) or as
// 1-byte bool (packed bytes -> many words > 1). Deterministic for the dataset.
// ---------------------------------------------------------------------------
__global__ void detect_int32_kernel(const unsigned int* __restrict__ lt,
                                    int* __restrict__ flag) {
    int tid = threadIdx.x;  // 64 threads
    unsigned int bad = 0;
    for (int i = tid; i < 1024; i += 64) bad |= (lt[i] > 1u) ? 1u : 0u;
    unsigned long long mask = __ballot(bad != 0);
    if (tid == 0) flag[0] = (mask == 0ULL) ? 1 : 0;  // 1 => int32 storage
}

__device__ inline void amax_comb(float& m, int& mi, float om, int omi) {
    // max value; ties -> smallest index (jnp.argmax takes first occurrence)
    if (om > m || (om == m && omi < mi)) { m = om; mi = omi; }
}

// ---------------------------------------------------------------------------
// Kernel 1: one block per row, 4 float4/thread (16 data VGPRs — proven to stay
// in registers). Thread-local online softmax: max + first-argmax + exp-sum
// against the LOCAL max, no barrier in the element path. One wave shuffle
// reduce (with one rescale), one LDS write, ONE barrier, thread-0 combine.
// Also builds the level-1 (bits 31:20) radix histogram for the top-k kernel.
// ---------------------------------------------------------------------------
__global__ __launch_bounds__(256) void row_loss_kernel(
    const float* __restrict__ yp, const int* __restrict__ yt,
    const unsigned char* __restrict__ lt, const int* __restrict__ flag,
    float* __restrict__ losses, unsigned int* __restrict__ hist) {
    const int b    = blockIdx.x;
    const int tid  = threadIdx.x;
    const int lane = tid & 63, wid = tid >> 6;

    const float4* rp = reinterpret_cast<const float4*>(yp + (size_t)b * NCLS);
    float4 c0 = rp[tid], c1 = rp[256 + tid], c2 = rp[512 + tid], c3 = rp[768 + tid];

    const int gt = yt[b];  // block-uniform scalar load

    __shared__ float wm[4];
    __shared__ float ws[4];
    __shared__ int   wi[4];
    __shared__ float s_true;

    // ---- thread-local max + FIRST argmax (ascending scan, strictly-greater)
    const int base = tid * 4;
    float m = c0.x; int mi = base;
    if (c0.y > m) { m = c0.y; mi = base + 1; }
    if (c0.z > m) { m = c0.z; mi = base + 2; }
    if (c0.w > m) { m = c0.w; mi = base + 3; }
    if (c1.x > m) { m = c1.x; mi = 1024 + base + 0; }
    if (c1.y > m) { m = c1.y; mi = 1024 + base + 1; }
    if (c1.z > m) { m = c1.z; mi = 1024 + base + 2; }
    if (c1.w > m) { m = c1.w; mi = 1024 + base + 3; }
    if (c2.x > m) { m = c2.x; mi = 2048 + base + 0; }
    if (c2.y > m) { m = c2.y; mi = 2048 + base + 1; }
    if (c2.z > m) { m = c2.z; mi = 2048 + base + 2; }
    if (c2.w > m) { m = c2.w; mi = 2048 + base + 3; }
    if (c3.x > m) { m = c3.x; mi = 3072 + base + 0; }
    if (c3.y > m) { m = c3.y; mi = 3072 + base + 1; }
    if (c3.z > m) { m = c3.z; mi = 3072 + base + 2; }
    if (c3.w > m) { m = c3.w; mi = 3072 + base + 3; }

    // ---- thread-local exp-sum against LOCAL max (no barrier needed)
    float sx = __expf(c0.x - m) + __expf(c1.x - m) + __expf(c2.x - m) + __expf(c3.x - m);
    float sy = __expf(c0.y - m) + __expf(c1.y - m) + __expf(c2.y - m) + __expf(c3.y - m);
    float sz = __expf(c0.z - m) + __expf(c1.z - m) + __expf(c2.z - m) + __expf(c3.z - m);
    float sw = __expf(c0.w - m) + __expf(c1.w - m) + __expf(c2.w - m) + __expf(c3.w - m);
    float s = (sx + sy) + (sz + sw);

    // ---- capture the true-class logit (owner thread, pre-barrier LDS write)
    if (tid == ((gt >> 2) & 255)) {
        const int j = gt >> 10, k = gt & 3;
        float4 vv = (j == 0) ? c0 : (j == 1) ? c1 : (j == 2) ? c2 : c3;
        s_true = (k == 0) ? vv.x : (k == 1) ? vv.y : (k == 2) ? vv.z : vv.w;
    }

    // ---- wave reduce: argmax combine, then single rescale + sum reduce
    float mw = m; int miw = mi;
    #pragma unroll
    for (int off = 32; off > 0; off >>= 1) {
        float om  = __shfl_xor(mw, off, 64);
        int   omi = __shfl_xor(miw, off, 64);
        amax_comb(mw, miw, om, omi);
    }
    s *= __expf(m - mw);                 // local max -> wave max, one exp
    #pragma unroll
    for (int off = 32; off > 0; off >>= 1) s += __shfl_xor(s, off, 64);

    if (lane == 0) { wm[wid] = mw; wi[wid] = miw; ws[wid] = s; }
    __syncthreads();                     // the ONLY barrier

    if (tid == 0) {
        float M = wm[0]; int P = wi[0];
        amax_comb(M, P, wm[1], wi[1]);
        amax_comb(M, P, wm[2], wi[2]);
        amax_comb(M, P, wm[3], wi[3]);
        const float tot = ws[0] * __expf(wm[0] - M) + ws[1] * __expf(wm[1] - M) +
                          ws[2] * __expf(wm[2] - M) + ws[3] * __expf(wm[3] - M);
        const float ce = logf(tot) + M - s_true;
        float factor = 1.0f;
        if (P != gt) {
            const size_t li = (size_t)gt * NCLS + (size_t)P;
            const int linked = flag[0] ? ((const int*)lt)[li] : (int)lt[li];
            if (linked) factor = ALPHA;
        }
        const float lv = factor * ce;
        losses[b] = lv;
        atomicAdd(&hist[__float_as_uint(lv) >> 20], 1u);
    }
}

// ---------------------------------------------------------------------------
// Kernel 2: exact mean of top-K. Level-1 hist comes precomputed; threshold
// scans are single-wave suffix-scan + ballot (no serial thread-0 loops).
// ---------------------------------------------------------------------------
__device__ inline void scan4096(const unsigned int* hist, unsigned int kneed,
                                int* s_bin, unsigned int* s_kneed, int tid) {
    if (tid < 64) {
        // stage 1: super-bins of 64
        unsigned int sb = 0;
        #pragma unroll 8
        for (int i = 0; i < 64; ++i) sb += hist[tid * 64 + i];
        unsigned int GS = sb;  // suffix sum over super-bins
        #pragma unroll
        for (int off = 1; off < 64; off <<= 1) {
            unsigned int o = __shfl_down(GS, off, 64);
            GS += (tid + off < 64) ? o : 0u;
        }
        unsigned long long b1 = __ballot(GS >= kneed);
        const int sstar = 63 - __clzll(b1);
        const unsigned int A1 = (sstar < 63) ? __shfl(GS, sstar + 1, 64) : 0u;

        // stage 2: within super-bin sstar
        unsigned int W = hist[sstar * 64 + tid];
        #pragma unroll
        for (int off = 1; off < 64; off <<= 1) {
            unsigned int o = __shfl_down(W, off, 64);
            W += (tid + off < 64) ? o : 0u;
        }
        unsigned long long b2 = __ballot(A1 + W >= kneed);
        const int tstar = 63 - __clzll(b2);
        const unsigned int above = A1 + ((tstar < 63) ? __shfl(W, tstar + 1, 64) : 0u);
        if (tid == 0) { *s_bin = sstar * 64 + tstar; *s_kneed = kneed - above; }
    }
}

__global__ __launch_bounds__(1024) void topk_mean_kernel(
    const float* __restrict__ losses, const unsigned int* __restrict__ ghist,
    float* __restrict__ out) {
    __shared__ unsigned int hist[4096];
    __shared__ int          s_bin;
    __shared__ unsigned int s_kneed;
    __shared__ double       dsum[16];
    __shared__ unsigned int dcnt[16];

    const int tid = threadIdx.x;
    const int N = BATCHN, K = TOPK;

    // ---- level 1: bits [31:20] (hist precomputed by row_loss)
    for (int i = tid; i < 4096; i += 1024) hist[i] = ghist[i];
    __syncthreads();
    scan4096(hist, (unsigned int)K, &s_bin, &s_kneed, tid);
    __syncthreads();
    const unsigned int t1 = (unsigned int)s_bin;
    const unsigned int k1 = s_kneed;
    __syncthreads();

    // ---- level 2: bits [19:8] among keys with key>>20 == t1
    for (int i = tid; i < 4096; i += 1024) hist[i] = 0;
    __syncthreads();
    for (int i = tid; i < N; i += 1024) {
        const unsigned int key = __float_as_uint(losses[i]);
        if ((key >> 20) == t1) atomicAdd(&hist[(key >> 8) & 0xFFFu], 1u);
    }
    __syncthreads();
    scan4096(hist, k1, &s_bin, &s_kneed, tid);
    __syncthreads();
    const unsigned int t2 = (unsigned int)s_bin;
    const unsigned int k2 = s_kneed;
    const unsigned int pref = (t1 << 12) | t2;  // 24-bit prefix
    __syncthreads();

    // ---- level 3: bits [7:0] among keys with key>>8 == pref
    for (int i = tid; i < 256; i += 1024) hist[i] = 0;
    __syncthreads();
    for (int i = tid; i < N; i += 1024) {
        const unsigned int key = __float_as_uint(losses[i]);
        if ((key >> 8) == pref) atomicAdd(&hist[key & 0xFFu], 1u);
    }
    __syncthreads();
    if (tid < 64) {
        // super-bins of 4
        unsigned int sb = hist[tid * 4] + hist[tid * 4 + 1] +
                          hist[tid * 4 + 2] + hist[tid * 4 + 3];
        unsigned int GS = sb;
        #pragma unroll
        for (int off = 1; off < 64; off <<= 1) {
            unsigned int o = __shfl_down(GS, off, 64);
            GS += (tid + off < 64) ? o : 0u;
        }
        unsigned long long b1 = __ballot(GS >= k2);
        const int sstar = 63 - __clzll(b1);
        const unsigned int A1 = (sstar < 63) ? __shfl(GS, sstar + 1, 64) : 0u;
        if (tid == 0) {
            unsigned int G = A1; int tstar = sstar * 4;
            for (int j = 3; j >= 0; --j) {
                const int bin = sstar * 4 + j;
                if (G + hist[bin] >= k2) { tstar = bin; break; }
                G += hist[bin];
            }
            s_bin = tstar;
        }
    }
    __syncthreads();
    const unsigned int T = (pref << 8) | (unsigned int)s_bin;  // threshold bits

    // ---- final: sum strictly-greater, fill remainder with T (ties)
    double local = 0.0; unsigned int cgt = 0;
    for (int i = tid; i < N; i += 1024) {
        const unsigned int key = __float_as_uint(losses[i]);
        if (key > T) { local += (double)__uint_as_float(key); cgt++; }
    }
    const int wid = tid >> 6, lane = tid & 63;
    #pragma unroll
    for (int off = 32; off > 0; off >>= 1) {
        local += __shfl_down(local, off, 64);
        cgt   += __shfl_down(cgt, off, 64);
    }
    if (lane == 0) { dsum[wid] = local; dcnt[wid] = cgt; }
    __syncthreads();
    if (tid == 0) {
        double tot = 0.0; unsigned int ngt = 0;
        for (int w = 0; w < 16; ++w) { tot += dsum[w]; ngt += dcnt[w]; }
        tot += (double)(K - ngt) * (double)__uint_as_float(T);
        out[0] = (float)(tot / (double)K);
    }
}

// ---------------------------------------------------------------------------
extern "C" void kernel_launch(void* const* d_in, const int* in_sizes, int n_in,
                              void* d_out, int out_size, void* d_ws, size_t ws_size,
                              hipStream_t stream) {
    const float* y_pred     = (const float*)d_in[0];
    const int* y_true       = (const int*)d_in[1];
    const unsigned char* lt = (const unsigned char*)d_in[2];
    float* out              = (float*)d_out;

    int*          flag   = (int*)d_ws;
    unsigned int* hist   = (unsigned int*)((char*)d_ws + 1024);          // 16 KB
    float*        losses = (float*)((char*)d_ws + 32768);                // 256 KB

    detect_int32_kernel<<<1, 64, 0, stream>>>((const unsigned int*)lt, flag);
    hipMemsetAsync(hist, 0, 4096 * sizeof(unsigned int), stream);
    row_loss_kernel<<<BATCHN, 256, 0, stream>>>(y_pred, y_true, lt, flag, losses, hist);
    topk_mean_kernel<<<1, 1024, 0, stream>>>(losses, hist, out);
}

// Round 5
// 299.043 us; speedup vs baseline: 2.6549x; 2.5277x over previous
//
#include <hip/hip_runtime.h>

#define NCLS   4096
#define BATCHN 65536
#define TOPK   4096
#define ALPHA  2.0f

// ---------------------------------------------------------------------------
// Kernel 0: detect whether link_table arrived as int32 (words all 0/1) or as
// 1-byte bool (packed bytes -> many words > 1). Deterministic for the dataset.
// ---------------------------------------------------------------------------
__global__ void detect_int32_kernel(const unsigned int* __restrict__ lt,
                                    int* __restrict__ flag) {
    int tid = threadIdx.x;  // 64 threads
    unsigned int bad = 0;
    for (int i = tid; i < 1024; i += 64) bad |= (lt[i] > 1u) ? 1u : 0u;
    unsigned long long mask = __ballot(bad != 0);
    if (tid == 0) flag[0] = (mask == 0ULL) ? 1 : 0;  // 1 => int32 storage
}

__device__ inline void amax_comb(float& m, int& mi, float om, int omi) {
    // max value; ties -> smallest index (jnp.argmax takes first occurrence)
    if (om > m || (om == m && omi < mi)) { m = om; mi = omi; }
}

// ---------------------------------------------------------------------------
// Kernel 1: one block per row, 4 float4/thread. Thread-local online softmax,
// one barrier. NO global atomics (they serialized at the fabric: 65536 far
// atomics x ~10ns = ~650us in rounds 2-4; WRITE_SIZE showed 65536 x 64B).
// ---------------------------------------------------------------------------
__global__ __launch_bounds__(256) void row_loss_kernel(
    const float* __restrict__ yp, const int* __restrict__ yt,
    const unsigned char* __restrict__ lt, const int* __restrict__ flag,
    float* __restrict__ losses) {
    const int b    = blockIdx.x;
    const int tid  = threadIdx.x;
    const int lane = tid & 63, wid = tid >> 6;

    const float4* rp = reinterpret_cast<const float4*>(yp + (size_t)b * NCLS);
    float4 c0 = rp[tid], c1 = rp[256 + tid], c2 = rp[512 + tid], c3 = rp[768 + tid];

    const int gt = yt[b];  // block-uniform scalar load

    __shared__ float wm[4];
    __shared__ float ws[4];
    __shared__ int   wi[4];
    __shared__ float s_true;

    // ---- thread-local max + FIRST argmax (ascending scan, strictly-greater)
    const int base = tid * 4;
    float m = c0.x; int mi = base;
    if (c0.y > m) { m = c0.y; mi = base + 1; }
    if (c0.z > m) { m = c0.z; mi = base + 2; }
    if (c0.w > m) { m = c0.w; mi = base + 3; }
    if (c1.x > m) { m = c1.x; mi = 1024 + base + 0; }
    if (c1.y > m) { m = c1.y; mi = 1024 + base + 1; }
    if (c1.z > m) { m = c1.z; mi = 1024 + base + 2; }
    if (c1.w > m) { m = c1.w; mi = 1024 + base + 3; }
    if (c2.x > m) { m = c2.x; mi = 2048 + base + 0; }
    if (c2.y > m) { m = c2.y; mi = 2048 + base + 1; }
    if (c2.z > m) { m = c2.z; mi = 2048 + base + 2; }
    if (c2.w > m) { m = c2.w; mi = 2048 + base + 3; }
    if (c3.x > m) { m = c3.x; mi = 3072 + base + 0; }
    if (c3.y > m) { m = c3.y; mi = 3072 + base + 1; }
    if (c3.z > m) { m = c3.z; mi = 3072 + base + 2; }
    if (c3.w > m) { m = c3.w; mi = 3072 + base + 3; }

    // ---- thread-local exp-sum against LOCAL max (no barrier needed)
    float sx = __expf(c0.x - m) + __expf(c1.x - m) + __expf(c2.x - m) + __expf(c3.x - m);
    float sy = __expf(c0.y - m) + __expf(c1.y - m) + __expf(c2.y - m) + __expf(c3.y - m);
    float sz = __expf(c0.z - m) + __expf(c1.z - m) + __expf(c2.z - m) + __expf(c3.z - m);
    float sw = __expf(c0.w - m) + __expf(c1.w - m) + __expf(c2.w - m) + __expf(c3.w - m);
    float s = (sx + sy) + (sz + sw);

    // ---- capture the true-class logit (owner thread, pre-barrier LDS write)
    if (tid == ((gt >> 2) & 255)) {
        const int j = gt >> 10, k = gt & 3;
        float4 vv = (j == 0) ? c0 : (j == 1) ? c1 : (j == 2) ? c2 : c3;
        s_true = (k == 0) ? vv.x : (k == 1) ? vv.y : (k == 2) ? vv.z : vv.w;
    }

    // ---- wave reduce: argmax combine, then single rescale + sum reduce
    float mw = m; int miw = mi;
    #pragma unroll
    for (int off = 32; off > 0; off >>= 1) {
        float om  = __shfl_xor(mw, off, 64);
        int   omi = __shfl_xor(miw, off, 64);
        amax_comb(mw, miw, om, omi);
    }
    s *= __expf(m - mw);                 // local max -> wave max, one exp
    #pragma unroll
    for (int off = 32; off > 0; off >>= 1) s += __shfl_xor(s, off, 64);

    if (lane == 0) { wm[wid] = mw; wi[wid] = miw; ws[wid] = s; }
    __syncthreads();                     // the ONLY barrier

    if (tid == 0) {
        float M = wm[0]; int P = wi[0];
        amax_comb(M, P, wm[1], wi[1]);
        amax_comb(M, P, wm[2], wi[2]);
        amax_comb(M, P, wm[3], wi[3]);
        const float tot = ws[0] * __expf(wm[0] - M) + ws[1] * __expf(wm[1] - M) +
                          ws[2] * __expf(wm[2] - M) + ws[3] * __expf(wm[3] - M);
        const float ce = logf(tot) + M - s_true;
        float factor = 1.0f;
        if (P != gt) {
            const size_t li = (size_t)gt * NCLS + (size_t)P;
            const int linked = flag[0] ? ((const int*)lt)[li] : (int)lt[li];
            if (linked) factor = ALPHA;
        }
        losses[b] = factor * ce;
    }
}

// ---------------------------------------------------------------------------
// Kernel 2: exact mean of top-K. Level-1 histogram built here with
// WAVE-AGGREGATED LDS atomics (leader-election ballot loop) because bins are
// highly concentrated; levels 2/3 use plain LDS atomics (uniform spread).
// ---------------------------------------------------------------------------
__device__ inline void scan4096(const unsigned int* hist, unsigned int kneed,
                                int* s_bin, unsigned int* s_kneed, int tid) {
    if (tid < 64) {
        // stage 1: super-bins of 64
        unsigned int sb = 0;
        #pragma unroll 8
        for (int i = 0; i < 64; ++i) sb += hist[tid * 64 + i];
        unsigned int GS = sb;  // suffix sum over super-bins
        #pragma unroll
        for (int off = 1; off < 64; off <<= 1) {
            unsigned int o = __shfl_down(GS, off, 64);
            GS += (tid + off < 64) ? o : 0u;
        }
        unsigned long long b1 = __ballot(GS >= kneed);
        const int sstar = 63 - __clzll(b1);
        const unsigned int A1 = (sstar < 63) ? __shfl(GS, sstar + 1, 64) : 0u;

        // stage 2: within super-bin sstar
        unsigned int W = hist[sstar * 64 + tid];
        #pragma unroll
        for (int off = 1; off < 64; off <<= 1) {
            unsigned int o = __shfl_down(W, off, 64);
            W += (tid + off < 64) ? o : 0u;
        }
        unsigned long long b2 = __ballot(A1 + W >= kneed);
        const int tstar = 63 - __clzll(b2);
        const unsigned int above = A1 + ((tstar < 63) ? __shfl(W, tstar + 1, 64) : 0u);
        if (tid == 0) { *s_bin = sstar * 64 + tstar; *s_kneed = kneed - above; }
    }
}

__global__ __launch_bounds__(1024) void topk_mean_kernel(
    const float* __restrict__ losses, float* __restrict__ out) {
    __shared__ unsigned int hist[4096];
    __shared__ int          s_bin;
    __shared__ unsigned int s_kneed;
    __shared__ double       dsum[16];
    __shared__ unsigned int dcnt[16];

    const int tid = threadIdx.x;
    const int lane = tid & 63;
    const int N = BATCHN, K = TOPK;

    // ---- level 1: bits [31:20], wave-aggregated LDS atomics
    for (int i = tid; i < 4096; i += 1024) hist[i] = 0;
    __syncthreads();
    for (int i = tid; i < N; i += 1024) {          // 64 full-wave iterations
        const unsigned int bin = __float_as_uint(losses[i]) >> 20;
        unsigned long long rem = __ballot(true);   // all 64 lanes active
        while (rem) {
            const int leader = __ffsll((unsigned long long)rem) - 1;
            const unsigned int lbin = __shfl(bin, leader, 64);
            const unsigned long long eq = __ballot(bin == lbin);
            if (lane == leader)
                atomicAdd(&hist[lbin], (unsigned int)__popcll(eq));
            rem &= ~eq;
        }
    }
    __syncthreads();
    scan4096(hist, (unsigned int)K, &s_bin, &s_kneed, tid);
    __syncthreads();
    const unsigned int t1 = (unsigned int)s_bin;
    const unsigned int k1 = s_kneed;
    __syncthreads();

    // ---- level 2: bits [19:8] among keys with key>>20 == t1
    for (int i = tid; i < 4096; i += 1024) hist[i] = 0;
    __syncthreads();
    for (int i = tid; i < N; i += 1024) {
        const unsigned int key = __float_as_uint(losses[i]);
        if ((key >> 20) == t1) atomicAdd(&hist[(key >> 8) & 0xFFFu], 1u);
    }
    __syncthreads();
    scan4096(hist, k1, &s_bin, &s_kneed, tid);
    __syncthreads();
    const unsigned int t2 = (unsigned int)s_bin;
    const unsigned int k2 = s_kneed;
    const unsigned int pref = (t1 << 12) | t2;  // 24-bit prefix
    __syncthreads();

    // ---- level 3: bits [7:0] among keys with key>>8 == pref
    for (int i = tid; i < 256; i += 1024) hist[i] = 0;
    __syncthreads();
    for (int i = tid; i < N; i += 1024) {
        const unsigned int key = __float_as_uint(losses[i]);
        if ((key >> 8) == pref) atomicAdd(&hist[key & 0xFFu], 1u);
    }
    __syncthreads();
    if (tid < 64) {
        // super-bins of 4
        unsigned int sb = hist[tid * 4] + hist[tid * 4 + 1] +
                          hist[tid * 4 + 2] + hist[tid * 4 + 3];
        unsigned int GS = sb;
        #pragma unroll
        for (int off = 1; off < 64; off <<= 1) {
            unsigned int o = __shfl_down(GS, off, 64);
            GS += (tid + off < 64) ? o : 0u;
        }
        unsigned long long b1 = __ballot(GS >= k2);
        const int sstar = 63 - __clzll(b1);
        const unsigned int A1 = (sstar < 63) ? __shfl(GS, sstar + 1, 64) : 0u;
        if (tid == 0) {
            unsigned int G = A1; int tstar = sstar * 4;
            for (int j = 3; j >= 0; --j) {
                const int bin = sstar * 4 + j;
                if (G + hist[bin] >= k2) { tstar = bin; break; }
                G += hist[bin];
            }
            s_bin = tstar;
        }
    }
    __syncthreads();
    const unsigned int T = (pref << 8) | (unsigned int)s_bin;  // threshold bits

    // ---- final: sum strictly-greater, fill remainder with T (ties)
    double local = 0.0; unsigned int cgt = 0;
    for (int i = tid; i < N; i += 1024) {
        const unsigned int key = __float_as_uint(losses[i]);
        if (key > T) { local += (double)__uint_as_float(key); cgt++; }
    }
    const int wid = tid >> 6;
    #pragma unroll
    for (int off = 32; off > 0; off >>= 1) {
        local += __shfl_down(local, off, 64);
        cgt   += __shfl_down(cgt, off, 64);
    }
    if (lane == 0) { dsum[wid] = local; dcnt[wid] = cgt; }
    __syncthreads();
    if (tid == 0) {
        double tot = 0.0; unsigned int ngt = 0;
        for (int w = 0; w < 16; ++w) { tot += dsum[w]; ngt += dcnt[w]; }
        tot += (double)(K - ngt) * (double)__uint_as_float(T);
        out[0] = (float)(tot / (double)K);
    }
}

// ---------------------------------------------------------------------------
extern "C" void kernel_launch(void* const* d_in, const int* in_sizes, int n_in,
                              void* d_out, int out_size, void* d_ws, size_t ws_size,
                              hipStream_t stream) {
    const float* y_pred     = (const float*)d_in[0];
    const int* y_true       = (const int*)d_in[1];
    const unsigned char* lt = (const unsigned char*)d_in[2];
    float* out              = (float*)d_out;

    int*   flag   = (int*)d_ws;
    float* losses = (float*)((char*)d_ws + 32768);   // 256 KB

    detect_int32_kernel<<<1, 64, 0, stream>>>((const unsigned int*)lt, flag);
    row_loss_kernel<<<BATCHN, 256, 0, stream>>>(y_pred, y_true, lt, flag, losses);
    topk_mean_kernel<<<1, 1024, 0, stream>>>(losses, out);
}